// Round 1
// 1566.326 us; speedup vs baseline: 1.0373x; 1.0373x over previous
//
#include <hip/hip_runtime.h>

// GCNConv: out = A_hat @ (X @ W + b)
// X [16384,512] f32, A_hat [16384,16384] f32, W [512,256] f32, b [256] f32
// k1: H^T = (X@W + b)^T as bf16 [256][16384] into d_ws (unchanged from prev round)
// k2 (rewritten): out = A_hat @ H
//    BM=64, BN=256(full), splitK=4 (kc chunk 4096), grid 1024 = m*4+kc (kc fast
//    -> each XCD's L2 holds exactly one 2MB HT chunk), 256 threads (4 waves,
//    wave tile 64x64), 3 blocks/CU.
//    B operand: direct global->VGPR fragment loads (HT already in B-frag layout),
//    1-tile register double-buffer, no LDS for B.
//    A operand: 8KB double-buffered LDS tile, f32->bf16 via v_cvt_pk_bf16_f32,
//    ONE __syncthreads per K-step.

typedef short bf16x8 __attribute__((ext_vector_type(8)));
typedef float f32x4 __attribute__((ext_vector_type(4)));

__device__ __forceinline__ unsigned f2bf(float f) {
  unsigned u = __float_as_uint(f);
  unsigned r = 0x7fffu + ((u >> 16) & 1u);
  return (u + r) >> 16;  // bf16 bits (RNE) in low 16
}
__device__ __forceinline__ unsigned pack2(float lo, float hi) {
  return f2bf(lo) | (f2bf(hi) << 16);
}
__device__ __forceinline__ unsigned cvtpk2(float lo, float hi) {
  unsigned r;
  asm("v_cvt_pk_bf16_f32 %0, %1, %2" : "=v"(r) : "v"(lo), "v"(hi));
  return r;  // RNE packed bf16x2
}

// ---------------- Kernel 1: H^T[n][m] = sum_k X[m][k] W[k][n] + b[n], bf16 ----
__global__ __launch_bounds__(256, 2)
void gcn_proj(const float* __restrict__ X, const float* __restrict__ W,
              const float* __restrict__ bias, unsigned short* __restrict__ HT) {
  __shared__ unsigned short Xs[128 * 40];
  __shared__ unsigned short Ws[128 * 40];
  const int tid = threadIdx.x;
  const int bx = blockIdx.x;
  const int m0 = (bx & 127) * 128;
  const int n0 = (bx >> 7) * 128;
  const int lane = tid & 63;
  const int w = tid >> 6;
  const int wm = (w & 1) * 64;
  const int wn = (w >> 1) * 64;
  const int ln = lane & 15;
  const int q = lane >> 4;

  f32x4 acc[4][4];
#pragma unroll
  for (int i = 0; i < 4; ++i)
#pragma unroll
    for (int j = 0; j < 4; ++j) acc[i][j] = (f32x4)0.0f;

  const int xr = tid >> 1;
  const int xh = (tid & 1) * 16;
  const int wk = tid >> 3;
  const int wng = (tid & 7) * 16;

  for (int ks = 0; ks < 512; ks += 32) {
    const float* xp = X + (size_t)(m0 + xr) * 512 + ks + xh;
    float4 x0 = *(const float4*)(xp + 0);
    float4 x1 = *(const float4*)(xp + 4);
    float4 x2 = *(const float4*)(xp + 8);
    float4 x3 = *(const float4*)(xp + 12);
    const float* wp = W + (size_t)(ks + wk) * 256 + n0 + wng;
    float4 w0 = *(const float4*)(wp + 0);
    float4 w1 = *(const float4*)(wp + 4);
    float4 w2 = *(const float4*)(wp + 8);
    float4 w3 = *(const float4*)(wp + 12);
    __syncthreads();
    unsigned* xd = (unsigned*)&Xs[xr * 40 + xh];
    xd[0] = pack2(x0.x, x0.y); xd[1] = pack2(x0.z, x0.w);
    xd[2] = pack2(x1.x, x1.y); xd[3] = pack2(x1.z, x1.w);
    xd[4] = pack2(x2.x, x2.y); xd[5] = pack2(x2.z, x2.w);
    xd[6] = pack2(x3.x, x3.y); xd[7] = pack2(x3.z, x3.w);
    const float wv[16] = {w0.x, w0.y, w0.z, w0.w, w1.x, w1.y, w1.z, w1.w,
                          w2.x, w2.y, w2.z, w2.w, w3.x, w3.y, w3.z, w3.w};
#pragma unroll
    for (int j = 0; j < 16; ++j)
      Ws[(wng + j) * 40 + wk] = (unsigned short)f2bf(wv[j]);
    __syncthreads();

    bf16x8 af[4], bfr[4];
#pragma unroll
    for (int i = 0; i < 4; ++i)
      af[i] = *(const bf16x8*)&Xs[(wm + i * 16 + ln) * 40 + q * 8];
#pragma unroll
    for (int j = 0; j < 4; ++j)
      bfr[j] = *(const bf16x8*)&Ws[(wn + j * 16 + ln) * 40 + q * 8];
#pragma unroll
    for (int i = 0; i < 4; ++i)
#pragma unroll
      for (int j = 0; j < 4; ++j)
        acc[i][j] = __builtin_amdgcn_mfma_f32_16x16x32_bf16(af[i], bfr[j], acc[i][j], 0, 0, 0);
  }

#pragma unroll
  for (int j = 0; j < 4; ++j) {
    const int n = n0 + wn + j * 16 + ln;
    const float bv = bias[n];
#pragma unroll
    for (int i = 0; i < 4; ++i) {
      const int m = m0 + wm + i * 16 + q * 4;
      uint2 p;
      p.x = pack2(acc[i][j][0] + bv, acc[i][j][1] + bv);
      p.y = pack2(acc[i][j][2] + bv, acc[i][j][3] + bv);
      *(uint2*)&HT[(size_t)n * 16384 + m] = p;
    }
  }
}

// ---------------- Kernel 2: out[m][n] += A_hat[m][k] H[k][n] --------------------
__global__ __launch_bounds__(256, 3)
void gcn_agg(const float* __restrict__ A, const unsigned short* __restrict__ HT,
             float* __restrict__ out) {
  __shared__ unsigned short As[2][64 * 32];  // 8 KB double-buffered A tile (bf16)
  const int tid = threadIdx.x;
  const int bx = blockIdx.x;
  const int m0 = (bx >> 2) * 64;     // 256 m-tiles
  const int kc = (bx & 3) * 4096;    // 4 K-chunks, kc fast -> one chunk per XCD
  const int lane = tid & 63;
  const int w = tid >> 6;            // wave 0..3 -> n-range w*64
  const int ln = lane & 15;
  const int q = lane >> 4;

  f32x4 acc[4][4];
#pragma unroll
  for (int i = 0; i < 4; ++i)
#pragma unroll
    for (int j = 0; j < 4; ++j) acc[i][j] = (f32x4)0.0f;

  // A staging: thread t -> row t>>2 (0..63), 8 consecutive k at (t&3)*8
  const int arow = tid >> 2;
  const int ak = (tid & 3) * 8;
  const float* ap = A + (size_t)(m0 + arow) * 16384 + kc + ak;
  unsigned short* aw = &As[0][arow * 32 + ak];

  // B fragment pointers (per-lane): HT[w*64 + j*16 + ln][kc + q*8 + ...]
  // HT row-major over k -> lane holds 8 k-contiguous bf16 = exact MFMA B-frag.
  const unsigned short* bp0 = HT + (size_t)(w * 64 + 0 + ln) * 16384 + kc + q * 8;
  const unsigned short* bp1 = bp0 + (size_t)16 * 16384;
  const unsigned short* bp2 = bp0 + (size_t)32 * 16384;
  const unsigned short* bp3 = bp0 + (size_t)48 * 16384;

  bf16x8 bA[4], bB[4];
  // prologue: tile 0 -> As[0] + bA
  {
    float4 a0 = *(const float4*)(ap);
    float4 a1 = *(const float4*)(ap + 4);
    bA[0] = *(const bf16x8*)(bp0);
    bA[1] = *(const bf16x8*)(bp1);
    bA[2] = *(const bf16x8*)(bp2);
    bA[3] = *(const bf16x8*)(bp3);
    uint4 p;
    p.x = cvtpk2(a0.x, a0.y); p.y = cvtpk2(a0.z, a0.w);
    p.z = cvtpk2(a1.x, a1.y); p.w = cvtpk2(a1.z, a1.w);
    *(uint4*)aw = p;
  }
  __syncthreads();

  constexpr int NT = 128;  // 4096 / 32
#pragma unroll 1
  for (int s = 0; s < NT; s += 2) {
    // ---- even step: compute tile s (As[0], bA); prefetch s+1 -> As[1], bB
    {
      const int t = s + 1;  // always < NT (NT even)
      float4 a0 = *(const float4*)(ap + t * 32);
      float4 a1 = *(const float4*)(ap + t * 32 + 4);
      bB[0] = *(const bf16x8*)(bp0 + t * 32);
      bB[1] = *(const bf16x8*)(bp1 + t * 32);
      bB[2] = *(const bf16x8*)(bp2 + t * 32);
      bB[3] = *(const bf16x8*)(bp3 + t * 32);
      bf16x8 af[4];
#pragma unroll
      for (int i = 0; i < 4; ++i)
        af[i] = *(const bf16x8*)&As[0][(i * 16 + ln) * 32 + q * 8];
#pragma unroll
      for (int i = 0; i < 4; ++i)
#pragma unroll
        for (int j = 0; j < 4; ++j)
          acc[i][j] = __builtin_amdgcn_mfma_f32_16x16x32_bf16(af[i], bA[j], acc[i][j], 0, 0, 0);
      uint4 p;
      p.x = cvtpk2(a0.x, a0.y); p.y = cvtpk2(a0.z, a0.w);
      p.z = cvtpk2(a1.x, a1.y); p.w = cvtpk2(a1.z, a1.w);
      *(uint4*)(aw + 64 * 32) = p;  // As[1]
      __syncthreads();
    }
    // ---- odd step: compute tile s+1 (As[1], bB); prefetch s+2 -> As[0], bA
    {
      const int t = s + 2;
      const bool more = t < NT;
      float4 a0, a1;
      if (more) {
        a0 = *(const float4*)(ap + t * 32);
        a1 = *(const float4*)(ap + t * 32 + 4);
        bA[0] = *(const bf16x8*)(bp0 + t * 32);
        bA[1] = *(const bf16x8*)(bp1 + t * 32);
        bA[2] = *(const bf16x8*)(bp2 + t * 32);
        bA[3] = *(const bf16x8*)(bp3 + t * 32);
      }
      bf16x8 af[4];
#pragma unroll
      for (int i = 0; i < 4; ++i)
        af[i] = *(const bf16x8*)&As[1][(i * 16 + ln) * 32 + q * 8];
#pragma unroll
      for (int i = 0; i < 4; ++i)
#pragma unroll
        for (int j = 0; j < 4; ++j)
          acc[i][j] = __builtin_amdgcn_mfma_f32_16x16x32_bf16(af[i], bB[j], acc[i][j], 0, 0, 0);
      if (more) {
        uint4 p;
        p.x = cvtpk2(a0.x, a0.y); p.y = cvtpk2(a0.z, a0.w);
        p.z = cvtpk2(a1.x, a1.y); p.w = cvtpk2(a1.z, a1.w);
        *(uint4*)aw = p;  // As[0]
        __syncthreads();
      }
    }
  }

  // epilogue: split-K partial -> atomic add into zeroed d_out
#pragma unroll
  for (int i = 0; i < 4; ++i) {
    const int m = m0 + i * 16 + q * 4;
#pragma unroll
    for (int j = 0; j < 4; ++j) {
      const int n = w * 64 + j * 16 + ln;
      float* op = out + (size_t)m * 256 + n;
      atomicAdd(op + 0 * 256, acc[i][j][0]);
      atomicAdd(op + 1 * 256, acc[i][j][1]);
      atomicAdd(op + 2 * 256, acc[i][j][2]);
      atomicAdd(op + 3 * 256, acc[i][j][3]);
    }
  }
}

extern "C" void kernel_launch(void* const* d_in, const int* in_sizes, int n_in,
                              void* d_out, int out_size, void* d_ws, size_t ws_size,
                              hipStream_t stream) {
  (void)in_sizes; (void)n_in; (void)ws_size;
  const float* X = (const float*)d_in[0];
  const float* A = (const float*)d_in[1];
  const float* W = (const float*)d_in[2];
  const float* b = (const float*)d_in[3];
  float* out = (float*)d_out;
  unsigned short* HT = (unsigned short*)d_ws;  // 256*16384 bf16 = 8 MB

  hipMemsetAsync(d_out, 0, (size_t)out_size * sizeof(float), stream);
  gcn_proj<<<dim3(256), dim3(256), 0, stream>>>(X, W, b, HT);
  gcn_agg<<<dim3(1024), dim3(256), 0, stream>>>(A, HT, out);
}